// Round 2
// baseline (784.121 us; speedup 1.0000x reference)
//
#include <hip/hip_runtime.h>
#include <cmath>

#define NNODES 4096
#define FDIM 512
#define DH 64
#define CAP 128
#define NBLK (NNODES / 4)   // 1024 blocks = 4 blocks/CU x 256 CUs, exactly resident

// 30 KB of LDS shared across phases via one struct (phase0 reuses h_s as feat_s)
struct SharedMem {
    float h_s[4][FDIM];     // 8 KB
    float part[4][4][DH];   // 4 KB
    float w_s[4][CAP][8];   // 16 KB
    int   js_s[4][CAP];     // 2 KB
};

// ---------------------------------------------------------------------------
// Grid-wide barrier. Safe because the grid is exactly co-resident
// (launch_bounds(256,4) + 30 KB LDS -> 4 blocks/CU, grid == 256*4).
// Device-scope atomics + threadfence handle cross-XCD L2 non-coherence.
// Counters are zeroed by a captured hipMemsetAsync each launch.
// ---------------------------------------------------------------------------
__device__ __forceinline__ void grid_barrier(int* ctr) {
    __syncthreads();
    if (threadIdx.x == 0) {
        __threadfence();   // release: make this block's global writes visible
        __hip_atomic_fetch_add(ctr, 1, __ATOMIC_ACQ_REL, __HIP_MEMORY_SCOPE_AGENT);
        while (__hip_atomic_load(ctr, __ATOMIC_ACQUIRE, __HIP_MEMORY_SCOPE_AGENT) < NBLK) {
            __builtin_amdgcn_s_sleep(2);
        }
        __threadfence();   // acquire: invalidate stale lines before reading others' writes
    }
    __syncthreads();
}

// ---------------------------------------------------------------------------
// agg_L + mm_{L+1} + proj phase (same structure as the R8 k_agg_mm).
// ---------------------------------------------------------------------------
template <int PROJ_H>
__device__ __forceinline__ void agg_mm_phase(
    SharedMem& sm, const int lane, const int wv, const int node,
    const float* __restrict__ x_in, const float* __restrict__ el_in,
    const float* __restrict__ er_in, const int* __restrict__ nbr,
    const int* __restrict__ deg, const float* __restrict__ bias_agg,
    const float* __restrict__ W, const float* __restrict__ al,
    const float* __restrict__ ar, float* __restrict__ x_out,
    float* __restrict__ el_out, float* __restrict__ er_out)
{
    const float bv = bias_agg[lane];

    // ---- Phase A: all 8 heads of one node per wave
    {
        const int nl = lane >> 3;      // neighbor slot 0..7
        const int hh = lane & 7;       // head 0..7
        const float eli = el_in[node * 8 + hh];
        const int dg = deg[node];
        const int* nb = nbr + (size_t)node * CAP;
        const int nr = (dg + 7) >> 3;

        const int nbr0 = nb[lane];
        const int nbr1 = nb[64 + lane];

        float denp = 0.f;
        for (int r = 0; r < nr; r++) {
            const int jj = r * 8 + nl;
            const int jraw = __shfl((jj & 64) ? nbr1 : nbr0, jj & 63, 64);
            const bool val = jj < dg;
            const int j = val ? jraw : 0;
            const float e = er_in[j * 8 + hh];
            float s = eli + e;
            s = s > 0.f ? s : 0.2f * s;
            const float w = val ? __expf(s) : 0.f;
            sm.w_s[wv][jj][hh] = w;
            if (hh == 0) sm.js_s[wv][jj] = j;
            denp += w;
        }
        denp += __shfl_xor(denp, 8, 64);
        denp += __shfl_xor(denp, 16, 64);
        denp += __shfl_xor(denp, 32, 64);

        float acc[8] = {0.f, 0.f, 0.f, 0.f, 0.f, 0.f, 0.f, 0.f};
        const int cmax = nr * 8;
        for (int c = 0; c < cmax; c += 8) {
#pragma unroll
            for (int u = 0; u < 8; u++) {
                const int j = sm.js_s[wv][c + u];
                float4 wa = *reinterpret_cast<const float4*>(&sm.w_s[wv][c + u][0]);
                float4 wb = *reinterpret_cast<const float4*>(&sm.w_s[wv][c + u][4]);
                float xv = x_in[(size_t)j * DH + lane];
                acc[0] = fmaf(wa.x, xv, acc[0]);
                acc[1] = fmaf(wa.y, xv, acc[1]);
                acc[2] = fmaf(wa.z, xv, acc[2]);
                acc[3] = fmaf(wa.w, xv, acc[3]);
                acc[4] = fmaf(wb.x, xv, acc[4]);
                acc[5] = fmaf(wb.y, xv, acc[5]);
                acc[6] = fmaf(wb.z, xv, acc[6]);
                acc[7] = fmaf(wb.w, xv, acc[7]);
            }
        }
#pragma unroll
        for (int h = 0; h < 8; h++) {
            float den = __shfl(denp, h, 64);
            float o = acc[h] / fmaxf(den, 1e-12f) + bv;
            o = o > 0.f ? o : __expf(o) - 1.f;     // elu
            sm.h_s[wv][h * DH + lane] = o;
        }
    }
    __syncthreads();

    // ---- Phase B: mm + proj from LDS (wave = K-quarter)
    float acc[4] = {0.f, 0.f, 0.f, 0.f};
    const int k0 = wv * (FDIM / 4);
    for (int k = k0; k < k0 + FDIM / 4; k += 8) {
        float w[8];
#pragma unroll
        for (int u = 0; u < 8; u++) w[u] = W[(k + u) * DH + lane];
#pragma unroll
        for (int r = 0; r < 4; r++) {
            float4 a0 = *reinterpret_cast<const float4*>(&sm.h_s[r][k]);
            float4 a1 = *reinterpret_cast<const float4*>(&sm.h_s[r][k + 4]);
            acc[r] = fmaf(a0.x, w[0], fmaf(a0.y, w[1], fmaf(a0.z, w[2], fmaf(a0.w, w[3], acc[r]))));
            acc[r] = fmaf(a1.x, w[4], fmaf(a1.y, w[5], fmaf(a1.z, w[6], fmaf(a1.w, w[7], acc[r]))));
        }
    }
    __syncthreads();   // h_s reuse barrier (part write below is fine, but keep order)
#pragma unroll
    for (int r = 0; r < 4; r++) sm.part[wv][r][lane] = acc[r];
    __syncthreads();

    float xv = sm.part[0][wv][lane] + sm.part[1][wv][lane]
             + sm.part[2][wv][lane] + sm.part[3][wv][lane];
    x_out[(size_t)node * DH + lane] = xv;
#pragma unroll
    for (int hh = 0; hh < PROJ_H; hh++) {
        float vl = xv * al[lane * PROJ_H + hh];
        float vr = xv * ar[lane * PROJ_H + hh];
#pragma unroll
        for (int off = 32; off >= 1; off >>= 1) {
            vl += __shfl_xor(vl, off, 64);
            vr += __shfl_xor(vr, off, 64);
        }
        if (lane == 0) {
            el_out[node * PROJ_H + hh] = vl;
            er_out[node * PROJ_H + hh] = vr;
        }
    }
}

// ---------------------------------------------------------------------------
// Fused persistent kernel: build+mm0 -> bar -> agg0+mm1 -> bar -> agg1+mm2
// -> bar -> final agg. 1024 blocks x 256 threads, exactly co-resident.
// ---------------------------------------------------------------------------
__global__ __launch_bounds__(256, 4) void k_fused(
    const float* __restrict__ adj, const float* __restrict__ feat,
    const float* __restrict__ W0, const float* __restrict__ al0,
    const float* __restrict__ ar0, const float* __restrict__ b0,
    const float* __restrict__ W1, const float* __restrict__ al1,
    const float* __restrict__ ar1, const float* __restrict__ b1,
    const float* __restrict__ W2, const float* __restrict__ al2,
    const float* __restrict__ ar2, const float* __restrict__ b2,
    int* __restrict__ nbr, int* __restrict__ deg,
    float* __restrict__ x0, float* __restrict__ x1,
    float* __restrict__ elA, float* __restrict__ erA,
    float* __restrict__ elB, float* __restrict__ erB,
    float* __restrict__ out, int* bar)
{
    __shared__ SharedMem sm;
    const int lane = threadIdx.x & 63;
    const int wv = threadIdx.x >> 6;
    const int node = blockIdx.x * 4 + wv;

    // ---- Phase 0a: neighbor-list build, ONE ROW PER WAVE (register compaction,
    // no atomics). Order within a row differs from the old build but the GAT
    // math is order-invariant (weights summed; CAP never truncates at deg~32).
    {
        const float4* arow = reinterpret_cast<const float4*>(adj + (size_t)node * NNODES);
        int* nrow = nbr + (size_t)node * CAP;
        const unsigned long long lmask = (1ull << lane) - 1ull;
        int cnt = 0;
#pragma unroll 4
        for (int t = 0; t < 16; t++) {
            float4 v = arow[t * 64 + lane];
            const int colbase = (t * 64 + lane) * 4;
            float vals[4] = {v.x, v.y, v.z, v.w};
#pragma unroll
            for (int e = 0; e < 4; e++) {
                bool nz = vals[e] != 0.f;
                unsigned long long m = __ballot(nz);
                if (m) {
                    if (nz) {
                        int idx = cnt + __popcll(m & lmask);
                        if (idx < CAP) nrow[idx] = colbase + e;
                    }
                    cnt += __popcll(m);
                }
            }
        }
        if (lane == 0) deg[node] = cnt < CAP ? cnt : CAP;
    }

    // ---- Phase 0b: mm0 + proj0 (feat staged to LDS; wave = K-quarter)
    {
        const int r0 = blockIdx.x * 4;
        const float4* fsrc = reinterpret_cast<const float4*>(feat + (size_t)r0 * FDIM);
        float4* fdst = reinterpret_cast<float4*>(&sm.h_s[0][0]);
        fdst[threadIdx.x] = fsrc[threadIdx.x];
        fdst[threadIdx.x + 256] = fsrc[threadIdx.x + 256];
        __syncthreads();

        float acc[4] = {0.f, 0.f, 0.f, 0.f};
        const int k0 = wv * (FDIM / 4);
        for (int k = k0; k < k0 + FDIM / 4; k += 8) {
            float w[8];
#pragma unroll
            for (int u = 0; u < 8; u++) w[u] = W0[(k + u) * DH + lane];
#pragma unroll
            for (int r = 0; r < 4; r++) {
                float4 a0 = *reinterpret_cast<const float4*>(&sm.h_s[r][k]);
                float4 a1 = *reinterpret_cast<const float4*>(&sm.h_s[r][k + 4]);
                acc[r] = fmaf(a0.x, w[0], fmaf(a0.y, w[1], fmaf(a0.z, w[2], fmaf(a0.w, w[3], acc[r]))));
                acc[r] = fmaf(a1.x, w[4], fmaf(a1.y, w[5], fmaf(a1.z, w[6], fmaf(a1.w, w[7], acc[r]))));
            }
        }
        __syncthreads();
#pragma unroll
        for (int r = 0; r < 4; r++) sm.part[wv][r][lane] = acc[r];
        __syncthreads();

        float xv = sm.part[0][wv][lane] + sm.part[1][wv][lane]
                 + sm.part[2][wv][lane] + sm.part[3][wv][lane];
        x0[(size_t)node * DH + lane] = xv;
#pragma unroll
        for (int hh = 0; hh < 8; hh++) {
            float vl = xv * al0[lane * 8 + hh];
            float vr = xv * ar0[lane * 8 + hh];
#pragma unroll
            for (int off = 32; off >= 1; off >>= 1) {
                vl += __shfl_xor(vl, off, 64);
                vr += __shfl_xor(vr, off, 64);
            }
            if (lane == 0) {
                elA[node * 8 + hh] = vl;
                erA[node * 8 + hh] = vr;
            }
        }
    }

    grid_barrier(&bar[0]);

    // ---- Phase 1: agg0 + mm1 + proj1
    agg_mm_phase<8>(sm, lane, wv, node, x0, elA, erA, nbr, deg, b0,
                    W1, al1, ar1, x1, elB, erB);

    grid_barrier(&bar[64]);

    // ---- Phase 2: agg1 + mm2 + proj2 (writes back into x0/elA/erA)
    agg_mm_phase<1>(sm, lane, wv, node, x1, elB, erB, nbr, deg, b1,
                    W2, al2, ar2, x0, elA, erA);

    grid_barrier(&bar[128]);

    // ---- Phase 3: final aggregate (H=1, no activation) -> out
    {
        const float eli = elA[node];
        const int dg = deg[node];
        const int* nb = nbr + (size_t)node * CAP;
        const int nbr0 = nb[lane];
        const int nbr1 = nb[64 + lane];
        const int nr = (dg + 63) >> 6;
        float* ws4 = &sm.w_s[wv][0][0];   // reuse LDS (128 floats)
        int*   js4 = sm.js_s[wv];
        float denp = 0.f;
        for (int r = 0; r < nr; r++) {
            const int jj = r * 64 + lane;
            const int jraw = r ? nbr1 : nbr0;
            const bool val = jj < dg;
            const int j = val ? jraw : 0;
            const float e = erA[j];
            float s = eli + e;
            s = s > 0.f ? s : 0.2f * s;
            const float w = val ? __expf(s) : 0.f;
            ws4[jj] = w;
            js4[jj] = j;
            denp += w;
        }
#pragma unroll
        for (int off = 32; off >= 1; off >>= 1) denp += __shfl_xor(denp, off, 64);

        float acc = 0.f;
        const int cmax = (dg + 7) & ~7;
        for (int c = 0; c < cmax; c += 8) {
#pragma unroll
            for (int u = 0; u < 8; u++) {
                const int j = js4[c + u];
                const float w = ws4[c + u];
                const float xv = x0[(size_t)j * DH + lane];
                acc = fmaf(w, xv, acc);
            }
        }
        out[(size_t)node * DH + lane] = acc / fmaxf(denp, 1e-12f) + b2[lane];
    }
}

// ---------------------------------------------------------------------------
extern "C" void kernel_launch(void* const* d_in, const int* in_sizes, int n_in,
                              void* d_out, int out_size, void* d_ws, size_t ws_size,
                              hipStream_t stream)
{
    const float* adj  = (const float*)d_in[0];
    const float* feat = (const float*)d_in[1];
    const float* W0   = (const float*)d_in[2];
    const float* al0  = (const float*)d_in[3];
    const float* ar0  = (const float*)d_in[4];
    const float* b0   = (const float*)d_in[5];
    const float* W1   = (const float*)d_in[6];
    const float* al1  = (const float*)d_in[7];
    const float* ar1  = (const float*)d_in[8];
    const float* b1   = (const float*)d_in[9];
    const float* W2   = (const float*)d_in[10];
    const float* al2  = (const float*)d_in[11];
    const float* ar2  = (const float*)d_in[12];
    const float* b2   = (const float*)d_in[13];
    float* out = (float*)d_out;

    char* ws = (char*)d_ws;
    int*   nbr = (int*)ws;   ws += (size_t)NNODES * CAP * sizeof(int);   // 2 MB
    int*   deg = (int*)ws;   ws += (size_t)NNODES * sizeof(int);         // 16 KB
    float* x0  = (float*)ws; ws += (size_t)NNODES * DH * sizeof(float);  // 1 MB
    float* x1  = (float*)ws; ws += (size_t)NNODES * DH * sizeof(float);  // 1 MB
    float* elA = (float*)ws; ws += (size_t)NNODES * 8 * sizeof(float);   // 128 KB
    float* erA = (float*)ws; ws += (size_t)NNODES * 8 * sizeof(float);   // 128 KB
    float* elB = (float*)ws; ws += (size_t)NNODES * 8 * sizeof(float);   // 128 KB
    float* erB = (float*)ws; ws += (size_t)NNODES * 8 * sizeof(float);   // 128 KB
    int*   bar = (int*)ws;   ws += 3 * 64 * sizeof(int);                 // barrier ctrs

    // Barrier counters live in poisoned workspace -> zero them (graph-capturable)
    hipMemsetAsync(bar, 0, 3 * 64 * sizeof(int), stream);

    k_fused<<<NBLK, 256, 0, stream>>>(
        adj, feat, W0, al0, ar0, b0, W1, al1, ar1, b1, W2, al2, ar2, b2,
        nbr, deg, x0, x1, elA, erA, elB, erB, out, bar);
}

// Round 3
// 590.627 us; speedup vs baseline: 1.3276x; 1.3276x over previous
//
#include <hip/hip_runtime.h>
#include <cmath>

#define NNODES 4096
#define FDIM 512
#define DH 64
#define CAP 128
#define NBLK (NNODES / 4)   // 1024 blocks = 4 blocks/CU x 256 CUs, exactly resident

// 30 KB of LDS shared across phases via one struct (phase0 reuses h_s as feat_s)
struct SharedMem {
    float h_s[4][FDIM];     // 8 KB
    float part[4][4][DH];   // 4 KB
    float w_s[4][CAP][8];   // 16 KB
    int   js_s[4][CAP];     // 2 KB
};

// ---------------------------------------------------------------------------
// Grid-wide barrier, R10 fix: RELAXED polling (agent-scope atomic load reads
// the coherence point for that line WITHOUT emitting a cache invalidate), and
// ONE acquire fence per wave after the block passes. The R9 version polled
// with ACQUIRE semantics -> buffer_inv per poll -> ~1000 waves invalidating
// their XCD's L1/L2 every ~128 cycles for the whole barrier window ->
// machine-wide cache poison (measured: 660 us, VALUBusy 4.9%).
// Release side: the arrive-add carries RELEASE (one L2 writeback per block,
// required for cross-XCD visibility).
// ---------------------------------------------------------------------------
__device__ __forceinline__ void grid_barrier(int* ctr) {
    __syncthreads();
    if (threadIdx.x == 0) {
        __hip_atomic_fetch_add(ctr, 1, __ATOMIC_RELEASE, __HIP_MEMORY_SCOPE_AGENT);
        while (__hip_atomic_load(ctr, __ATOMIC_RELAXED, __HIP_MEMORY_SCOPE_AGENT) < NBLK) {
            __builtin_amdgcn_s_sleep(8);   // ~512 cy between polls
        }
    }
    __syncthreads();
    // one invalidate per wave, after everyone is past the arrive point
    __builtin_amdgcn_fence(__ATOMIC_ACQUIRE, "agent");
}

// ---------------------------------------------------------------------------
// agg_L + mm_{L+1} + proj phase (same structure as the R8 k_agg_mm).
// ---------------------------------------------------------------------------
template <int PROJ_H>
__device__ __forceinline__ void agg_mm_phase(
    SharedMem& sm, const int lane, const int wv, const int node,
    const float* __restrict__ x_in, const float* __restrict__ el_in,
    const float* __restrict__ er_in, const int* __restrict__ nbr,
    const int* __restrict__ deg, const float* __restrict__ bias_agg,
    const float* __restrict__ W, const float* __restrict__ al,
    const float* __restrict__ ar, float* __restrict__ x_out,
    float* __restrict__ el_out, float* __restrict__ er_out)
{
    const float bv = bias_agg[lane];

    // ---- Phase A: all 8 heads of one node per wave
    {
        const int nl = lane >> 3;      // neighbor slot 0..7
        const int hh = lane & 7;       // head 0..7
        const float eli = el_in[node * 8 + hh];
        const int dg = deg[node];
        const int* nb = nbr + (size_t)node * CAP;
        const int nr = (dg + 7) >> 3;

        const int nbr0 = nb[lane];
        const int nbr1 = nb[64 + lane];

        float denp = 0.f;
        for (int r = 0; r < nr; r++) {
            const int jj = r * 8 + nl;
            const int jraw = __shfl((jj & 64) ? nbr1 : nbr0, jj & 63, 64);
            const bool val = jj < dg;
            const int j = val ? jraw : 0;
            const float e = er_in[j * 8 + hh];
            float s = eli + e;
            s = s > 0.f ? s : 0.2f * s;
            const float w = val ? __expf(s) : 0.f;
            sm.w_s[wv][jj][hh] = w;
            if (hh == 0) sm.js_s[wv][jj] = j;
            denp += w;
        }
        denp += __shfl_xor(denp, 8, 64);
        denp += __shfl_xor(denp, 16, 64);
        denp += __shfl_xor(denp, 32, 64);

        float acc[8] = {0.f, 0.f, 0.f, 0.f, 0.f, 0.f, 0.f, 0.f};
        const int cmax = nr * 8;
        for (int c = 0; c < cmax; c += 8) {
#pragma unroll
            for (int u = 0; u < 8; u++) {
                const int j = sm.js_s[wv][c + u];
                float4 wa = *reinterpret_cast<const float4*>(&sm.w_s[wv][c + u][0]);
                float4 wb = *reinterpret_cast<const float4*>(&sm.w_s[wv][c + u][4]);
                float xv = x_in[(size_t)j * DH + lane];
                acc[0] = fmaf(wa.x, xv, acc[0]);
                acc[1] = fmaf(wa.y, xv, acc[1]);
                acc[2] = fmaf(wa.z, xv, acc[2]);
                acc[3] = fmaf(wa.w, xv, acc[3]);
                acc[4] = fmaf(wb.x, xv, acc[4]);
                acc[5] = fmaf(wb.y, xv, acc[5]);
                acc[6] = fmaf(wb.z, xv, acc[6]);
                acc[7] = fmaf(wb.w, xv, acc[7]);
            }
        }
#pragma unroll
        for (int h = 0; h < 8; h++) {
            float den = __shfl(denp, h, 64);
            float o = acc[h] / fmaxf(den, 1e-12f) + bv;
            o = o > 0.f ? o : __expf(o) - 1.f;     // elu
            sm.h_s[wv][h * DH + lane] = o;
        }
    }
    __syncthreads();

    // ---- Phase B: mm + proj from LDS (wave = K-quarter)
    float acc[4] = {0.f, 0.f, 0.f, 0.f};
    const int k0 = wv * (FDIM / 4);
    for (int k = k0; k < k0 + FDIM / 4; k += 8) {
        float w[8];
#pragma unroll
        for (int u = 0; u < 8; u++) w[u] = W[(k + u) * DH + lane];
#pragma unroll
        for (int r = 0; r < 4; r++) {
            float4 a0 = *reinterpret_cast<const float4*>(&sm.h_s[r][k]);
            float4 a1 = *reinterpret_cast<const float4*>(&sm.h_s[r][k + 4]);
            acc[r] = fmaf(a0.x, w[0], fmaf(a0.y, w[1], fmaf(a0.z, w[2], fmaf(a0.w, w[3], acc[r]))));
            acc[r] = fmaf(a1.x, w[4], fmaf(a1.y, w[5], fmaf(a1.z, w[6], fmaf(a1.w, w[7], acc[r]))));
        }
    }
    __syncthreads();   // h_s reads done before part/h_s reuse below
#pragma unroll
    for (int r = 0; r < 4; r++) sm.part[wv][r][lane] = acc[r];
    __syncthreads();

    float xv = sm.part[0][wv][lane] + sm.part[1][wv][lane]
             + sm.part[2][wv][lane] + sm.part[3][wv][lane];
    x_out[(size_t)node * DH + lane] = xv;
#pragma unroll
    for (int hh = 0; hh < PROJ_H; hh++) {
        float vl = xv * al[lane * PROJ_H + hh];
        float vr = xv * ar[lane * PROJ_H + hh];
#pragma unroll
        for (int off = 32; off >= 1; off >>= 1) {
            vl += __shfl_xor(vl, off, 64);
            vr += __shfl_xor(vr, off, 64);
        }
        if (lane == 0) {
            el_out[node * PROJ_H + hh] = vl;
            er_out[node * PROJ_H + hh] = vr;
        }
    }
}

// ---------------------------------------------------------------------------
// Fused persistent kernel: build+mm0 -> bar -> agg0+mm1 -> bar -> agg1+mm2
// -> bar -> final agg. 1024 blocks x 256 threads, exactly co-resident
// (R2 measured occupancy 49% = 4 blocks/CU resident; VGPR=64, LDS=30KB).
// ---------------------------------------------------------------------------
__global__ __launch_bounds__(256, 4) void k_fused(
    const float* __restrict__ adj, const float* __restrict__ feat,
    const float* __restrict__ W0, const float* __restrict__ al0,
    const float* __restrict__ ar0, const float* __restrict__ b0,
    const float* __restrict__ W1, const float* __restrict__ al1,
    const float* __restrict__ ar1, const float* __restrict__ b1,
    const float* __restrict__ W2, const float* __restrict__ al2,
    const float* __restrict__ ar2, const float* __restrict__ b2,
    int* __restrict__ nbr, int* __restrict__ deg,
    float* __restrict__ x0, float* __restrict__ x1,
    float* __restrict__ elA, float* __restrict__ erA,
    float* __restrict__ elB, float* __restrict__ erB,
    float* __restrict__ out, int* bar)
{
    __shared__ SharedMem sm;
    const int lane = threadIdx.x & 63;
    const int wv = threadIdx.x >> 6;
    const int node = blockIdx.x * 4 + wv;

    // ---- Phase 0a: neighbor-list build, one row per wave (register
    // compaction, no atomics). Order-invariant math; CAP never truncates
    // at deg~Poisson(32).
    {
        const float4* arow = reinterpret_cast<const float4*>(adj + (size_t)node * NNODES);
        int* nrow = nbr + (size_t)node * CAP;
        const unsigned long long lmask = (1ull << lane) - 1ull;
        int cnt = 0;
#pragma unroll 4
        for (int t = 0; t < 16; t++) {
            float4 v = arow[t * 64 + lane];
            const int colbase = (t * 64 + lane) * 4;
            float vals[4] = {v.x, v.y, v.z, v.w};
#pragma unroll
            for (int e = 0; e < 4; e++) {
                bool nz = vals[e] != 0.f;
                unsigned long long m = __ballot(nz);
                if (m) {
                    if (nz) {
                        int idx = cnt + __popcll(m & lmask);
                        if (idx < CAP) nrow[idx] = colbase + e;
                    }
                    cnt += __popcll(m);
                }
            }
        }
        if (lane == 0) deg[node] = cnt < CAP ? cnt : CAP;
    }

    // ---- Phase 0b: mm0 + proj0 (feat staged to LDS; wave = K-quarter)
    {
        const int r0 = blockIdx.x * 4;
        const float4* fsrc = reinterpret_cast<const float4*>(feat + (size_t)r0 * FDIM);
        float4* fdst = reinterpret_cast<float4*>(&sm.h_s[0][0]);
        fdst[threadIdx.x] = fsrc[threadIdx.x];
        fdst[threadIdx.x + 256] = fsrc[threadIdx.x + 256];
        __syncthreads();

        float acc[4] = {0.f, 0.f, 0.f, 0.f};
        const int k0 = wv * (FDIM / 4);
        for (int k = k0; k < k0 + FDIM / 4; k += 8) {
            float w[8];
#pragma unroll
            for (int u = 0; u < 8; u++) w[u] = W0[(k + u) * DH + lane];
#pragma unroll
            for (int r = 0; r < 4; r++) {
                float4 a0 = *reinterpret_cast<const float4*>(&sm.h_s[r][k]);
                float4 a1 = *reinterpret_cast<const float4*>(&sm.h_s[r][k + 4]);
                acc[r] = fmaf(a0.x, w[0], fmaf(a0.y, w[1], fmaf(a0.z, w[2], fmaf(a0.w, w[3], acc[r]))));
                acc[r] = fmaf(a1.x, w[4], fmaf(a1.y, w[5], fmaf(a1.z, w[6], fmaf(a1.w, w[7], acc[r]))));
            }
        }
        __syncthreads();
#pragma unroll
        for (int r = 0; r < 4; r++) sm.part[wv][r][lane] = acc[r];
        __syncthreads();

        float xv = sm.part[0][wv][lane] + sm.part[1][wv][lane]
                 + sm.part[2][wv][lane] + sm.part[3][wv][lane];
        x0[(size_t)node * DH + lane] = xv;
#pragma unroll
        for (int hh = 0; hh < 8; hh++) {
            float vl = xv * al0[lane * 8 + hh];
            float vr = xv * ar0[lane * 8 + hh];
#pragma unroll
            for (int off = 32; off >= 1; off >>= 1) {
                vl += __shfl_xor(vl, off, 64);
                vr += __shfl_xor(vr, off, 64);
            }
            if (lane == 0) {
                elA[node * 8 + hh] = vl;
                erA[node * 8 + hh] = vr;
            }
        }
    }

    grid_barrier(&bar[0]);

    // ---- Phase 1: agg0 + mm1 + proj1
    agg_mm_phase<8>(sm, lane, wv, node, x0, elA, erA, nbr, deg, b0,
                    W1, al1, ar1, x1, elB, erB);

    grid_barrier(&bar[64]);

    // ---- Phase 2: agg1 + mm2 + proj2 (writes back into x0/elA/erA)
    agg_mm_phase<1>(sm, lane, wv, node, x1, elB, erB, nbr, deg, b1,
                    W2, al2, ar2, x0, elA, erA);

    grid_barrier(&bar[128]);

    // ---- Phase 3: final aggregate (H=1, no activation) -> out
    {
        const float eli = elA[node];
        const int dg = deg[node];
        const int* nb = nbr + (size_t)node * CAP;
        const int nbr0 = nb[lane];
        const int nbr1 = nb[64 + lane];
        const int nr = (dg + 63) >> 6;
        float* ws4 = &sm.w_s[wv][0][0];   // reuse LDS (128 floats)
        int*   js4 = sm.js_s[wv];
        float denp = 0.f;
        for (int r = 0; r < nr; r++) {
            const int jj = r * 64 + lane;
            const int jraw = r ? nbr1 : nbr0;
            const bool val = jj < dg;
            const int j = val ? jraw : 0;
            const float e = erA[j];
            float s = eli + e;
            s = s > 0.f ? s : 0.2f * s;
            const float w = val ? __expf(s) : 0.f;
            ws4[jj] = w;
            js4[jj] = j;
            denp += w;
        }
#pragma unroll
        for (int off = 32; off >= 1; off >>= 1) denp += __shfl_xor(denp, off, 64);

        float acc = 0.f;
        const int cmax = (dg + 7) & ~7;
        for (int c = 0; c < cmax; c += 8) {
#pragma unroll
            for (int u = 0; u < 8; u++) {
                const int j = js4[c + u];
                const float w = ws4[c + u];
                const float xv = x0[(size_t)j * DH + lane];
                acc = fmaf(w, xv, acc);
            }
        }
        out[(size_t)node * DH + lane] = acc / fmaxf(denp, 1e-12f) + b2[lane];
    }
}

// ---------------------------------------------------------------------------
extern "C" void kernel_launch(void* const* d_in, const int* in_sizes, int n_in,
                              void* d_out, int out_size, void* d_ws, size_t ws_size,
                              hipStream_t stream)
{
    const float* adj  = (const float*)d_in[0];
    const float* feat = (const float*)d_in[1];
    const float* W0   = (const float*)d_in[2];
    const float* al0  = (const float*)d_in[3];
    const float* ar0  = (const float*)d_in[4];
    const float* b0   = (const float*)d_in[5];
    const float* W1   = (const float*)d_in[6];
    const float* al1  = (const float*)d_in[7];
    const float* ar1  = (const float*)d_in[8];
    const float* b1   = (const float*)d_in[9];
    const float* W2   = (const float*)d_in[10];
    const float* al2  = (const float*)d_in[11];
    const float* ar2  = (const float*)d_in[12];
    const float* b2   = (const float*)d_in[13];
    float* out = (float*)d_out;

    char* ws = (char*)d_ws;
    int*   nbr = (int*)ws;   ws += (size_t)NNODES * CAP * sizeof(int);   // 2 MB
    int*   deg = (int*)ws;   ws += (size_t)NNODES * sizeof(int);         // 16 KB
    float* x0  = (float*)ws; ws += (size_t)NNODES * DH * sizeof(float);  // 1 MB
    float* x1  = (float*)ws; ws += (size_t)NNODES * DH * sizeof(float);  // 1 MB
    float* elA = (float*)ws; ws += (size_t)NNODES * 8 * sizeof(float);   // 128 KB
    float* erA = (float*)ws; ws += (size_t)NNODES * 8 * sizeof(float);   // 128 KB
    float* elB = (float*)ws; ws += (size_t)NNODES * 8 * sizeof(float);   // 128 KB
    float* erB = (float*)ws; ws += (size_t)NNODES * 8 * sizeof(float);   // 128 KB
    int*   bar = (int*)ws;   ws += 3 * 64 * sizeof(int);                 // barrier ctrs

    // Barrier counters live in poisoned workspace -> zero them (graph-capturable)
    hipMemsetAsync(bar, 0, 3 * 64 * sizeof(int), stream);

    k_fused<<<NBLK, 256, 0, stream>>>(
        adj, feat, W0, al0, ar0, b0, W1, al1, ar1, b1, W2, al2, ar2, b2,
        nbr, deg, x0, x1, elA, erA, elB, erB, out, bar);
}

// Round 5
// 179.642 us; speedup vs baseline: 4.3649x; 3.2878x over previous
//
#include <hip/hip_runtime.h>
#include <cmath>

#define NNODES 4096
#define FDIM 512
#define DH 64
#define CAP 128

// ---------------------------------------------------------------------------
// R12: persistent-kernel arc abandoned (660 -> 503 us, barrier cache
// maintenance is O(100us) each no matter the spelling; R11 risked a hang).
// Kernel dispatch boundaries ARE the cheap grid barrier on MI355X.
// This round: 4-kernel structure restored; k_agg_mm occupancy doubled
// (2 nodes/block, head-split -> 2048 blocks x 15KB LDS = 8 blocks/CU =
// 32 waves/CU, the HW max; was 4 blocks/CU).
// ---------------------------------------------------------------------------

// ---------------------------------------------------------------------------
// Kernel 1 (heterogeneous): blocks [0,1024) run layer-0 mm+proj; blocks
// [1024,1024+4096) build neighbor lists (one block per adjacency row).
// Unchanged (near its 64 MB HBM floor).
// ---------------------------------------------------------------------------
__global__ __launch_bounds__(256) void k_mm0_build(
    const float* __restrict__ adj, int* __restrict__ nbr, int* __restrict__ deg,
    const float* __restrict__ feat, const float* __restrict__ W0,
    const float* __restrict__ al0, const float* __restrict__ ar0,
    float* __restrict__ x, float* __restrict__ el, float* __restrict__ er)
{
    __shared__ float feat_s[4][FDIM];   // 8 KB (mm role)
    __shared__ float part[4][4][DH];    // 4 KB (mm role)
    __shared__ int cnt;                 // build role
    const int lane = threadIdx.x & 63;

    if (blockIdx.x >= NNODES / 4) {
        const int row = blockIdx.x - NNODES / 4;
        if (threadIdx.x == 0) cnt = 0;
        __syncthreads();
        const float4* arow = reinterpret_cast<const float4*>(adj + (size_t)row * NNODES);
        int* nrow = nbr + (size_t)row * CAP;
        float4 v[4];
        v[0] = arow[threadIdx.x];
        v[1] = arow[threadIdx.x + 256];
        v[2] = arow[threadIdx.x + 512];
        v[3] = arow[threadIdx.x + 768];
        const unsigned long long lmask = (1ull << lane) - 1ull;
#pragma unroll
        for (int s = 0; s < 4; s++) {
            const int colbase = (threadIdx.x + s * 256) * 4;
            float vals[4] = {v[s].x, v[s].y, v[s].z, v[s].w};
#pragma unroll
            for (int e = 0; e < 4; e++) {
                bool nz = vals[e] != 0.f;
                unsigned long long m = __ballot(nz);
                if (m) {
                    int base = 0;
                    if (lane == 0) base = atomicAdd(&cnt, __popcll(m));
                    base = __shfl(base, 0, 64);
                    if (nz) {
                        int idx = base + __popcll(m & lmask);
                        if (idx < CAP) nrow[idx] = colbase + e;
                    }
                }
            }
        }
        __syncthreads();
        if (threadIdx.x == 0) deg[row] = cnt < CAP ? cnt : CAP;
        return;
    }

    // ---- mm0+proj0: 4 nodes per block, wave = K-quarter, feat from LDS
    const int kq = threadIdx.x >> 6;
    const int r0 = blockIdx.x * 4;
    {
        const float4* fsrc = reinterpret_cast<const float4*>(feat + (size_t)r0 * FDIM);
        float4* fdst = reinterpret_cast<float4*>(&feat_s[0][0]);
        fdst[threadIdx.x] = fsrc[threadIdx.x];
        fdst[threadIdx.x + 256] = fsrc[threadIdx.x + 256];
    }
    __syncthreads();

    float acc[4] = {0.f, 0.f, 0.f, 0.f};
    const int k0 = kq * (FDIM / 4);
    for (int k = k0; k < k0 + FDIM / 4; k += 8) {
        float w[8];
#pragma unroll
        for (int u = 0; u < 8; u++) w[u] = W0[(k + u) * DH + lane];
#pragma unroll
        for (int r = 0; r < 4; r++) {
            float4 a0 = *reinterpret_cast<const float4*>(&feat_s[r][k]);
            float4 a1 = *reinterpret_cast<const float4*>(&feat_s[r][k + 4]);
            acc[r] = fmaf(a0.x, w[0], fmaf(a0.y, w[1], fmaf(a0.z, w[2], fmaf(a0.w, w[3], acc[r]))));
            acc[r] = fmaf(a1.x, w[4], fmaf(a1.y, w[5], fmaf(a1.z, w[6], fmaf(a1.w, w[7], acc[r]))));
        }
    }
    __syncthreads();
#pragma unroll
    for (int r = 0; r < 4; r++) part[kq][r][lane] = acc[r];
    __syncthreads();

    float xv = part[0][kq][lane] + part[1][kq][lane] + part[2][kq][lane] + part[3][kq][lane];
    const int node = r0 + kq;
    x[(size_t)node * DH + lane] = xv;
#pragma unroll
    for (int hh = 0; hh < 8; hh++) {
        float vl = xv * al0[lane * 8 + hh];
        float vr = xv * ar0[lane * 8 + hh];
#pragma unroll
        for (int off = 32; off >= 1; off >>= 1) {
            vl += __shfl_xor(vl, off, 64);
            vr += __shfl_xor(vr, off, 64);
        }
        if (lane == 0) {
            el[node * 8 + hh] = vl;
            er[node * 8 + hh] = vr;
        }
    }
}

// ---------------------------------------------------------------------------
// Kernel 2/3 (fused agg_L + mm_{L+1} + proj), R12 occupancy restructure:
// block = 2 nodes, 4 waves = 2 nodes x 2 head-halves (4 heads per wave).
// Grid 2048, LDS 15 KB -> 8 blocks/CU = 32 waves/CU (HW max; was 4 blk/CU).
// Phase A per wave (node nd, head-half hf):
//   weight pass: lane = (slot 0..15) x (local head 0..3); rounds of 16
//     independent; padded slots w=0/j=0; no cross-wave LDS dependency
//     (each wave writes and reads only its own 4 head columns of w_s).
//   aggregate: {LDS broadcast j, broadcast float4 of 4 head weights,
//     coalesced x gather, 4 fma} unrolled 8-deep. x rows gathered twice
//     per node (once per half) — ~2us extra L2 traffic, buys 2x TLP.
// Phase B: mm over FDIM for the block's 2 nodes (wave = K-quarter), then
//   waves 0,1 reduce partials + el/er proj for node 0,1.
// ---------------------------------------------------------------------------
template <int PROJ_H>
__global__ __launch_bounds__(256, 8) void k_agg_mm(
    const float* __restrict__ x_in, const float* __restrict__ el_in,
    const float* __restrict__ er_in, const int* __restrict__ nbr,
    const int* __restrict__ deg, const float* __restrict__ bias_agg,
    const float* __restrict__ W, const float* __restrict__ al,
    const float* __restrict__ ar, float* __restrict__ x_out,
    float* __restrict__ el_out, float* __restrict__ er_out)
{
    __shared__ float h_s[2][FDIM];     // 4 KB
    __shared__ float part[4][2][DH];   // 2 KB
    __shared__ float w_s[2][CAP][8];   // 8 KB
    __shared__ int   js_s[2][CAP];     // 1 KB
    const int lane = threadIdx.x & 63;
    const int wv = threadIdx.x >> 6;   // 0..3
    const int nd = wv >> 1;            // node within block 0..1
    const int hf = wv & 1;             // head-half 0..1
    const int node = blockIdx.x * 2 + nd;
    const float bv = bias_agg[lane];

    // ---- Phase A: 4 heads of one node per wave
    {
        const int nl = lane >> 2;              // neighbor slot 0..15
        const int hh = hf * 4 + (lane & 3);    // global head 0..7
        const float eli = el_in[node * 8 + hh];
        const int dg = deg[node];
        const int* nb = nbr + (size_t)node * CAP;
        const int nr = (dg + 15) >> 4;         // rounds of 16 neighbors

        // neighbor list -> registers (coalesced; entries >= dg unused)
        const int nbr0 = nb[lane];
        const int nbr1 = nb[64 + lane];

        // weight pass: rounds independent; er-gather is the only load
        float denp = 0.f;
        for (int r = 0; r < nr; r++) {
            const int jj = r * 16 + nl;                      // 0..127
            const int jraw = __shfl((jj & 64) ? nbr1 : nbr0, jj & 63, 64);
            const bool val = jj < dg;
            const int j = val ? jraw : 0;                    // pad -> row 0
            const float e = er_in[j * 8 + hh];
            float s = eli + e;
            s = s > 0.f ? s : 0.2f * s;
            const float w = val ? __expf(s) : 0.f;
            w_s[nd][jj][hh] = w;
            if ((lane & 3) == 0) js_s[nd][jj] = j;  // both halves write same value
            denp += w;
        }
        // reduce den over slot lanes (bits 2..5); every lane then holds
        // den for its head hf*4+(lane&3); lanes 0..3 are canonical
        denp += __shfl_xor(denp, 4, 64);
        denp += __shfl_xor(denp, 8, 64);
        denp += __shfl_xor(denp, 16, 64);
        denp += __shfl_xor(denp, 32, 64);

        // aggregate pass: pure pipelined gather+fma (padded w=0 slots inert)
        float acc[4] = {0.f, 0.f, 0.f, 0.f};
        const int cmax = nr * 16;
        for (int c = 0; c < cmax; c += 8) {
#pragma unroll
            for (int u = 0; u < 8; u++) {
                const int j = js_s[nd][c + u];
                float4 wa = *reinterpret_cast<const float4*>(&w_s[nd][c + u][hf * 4]);
                float xv = x_in[(size_t)j * DH + lane];
                acc[0] = fmaf(wa.x, xv, acc[0]);
                acc[1] = fmaf(wa.y, xv, acc[1]);
                acc[2] = fmaf(wa.z, xv, acc[2]);
                acc[3] = fmaf(wa.w, xv, acc[3]);
            }
        }
#pragma unroll
        for (int h = 0; h < 4; h++) {
            float den = __shfl(denp, h, 64);   // lane h holds head hf*4+h
            float o = acc[h] / fmaxf(den, 1e-12f) + bv;
            o = o > 0.f ? o : __expf(o) - 1.f;     // elu
            h_s[nd][(hf * 4 + h) * DH + lane] = o;
        }
    }
    __syncthreads();

    // ---- Phase B: mm + proj from LDS (wave = K-quarter, 2 nodes)
    float acc2[2] = {0.f, 0.f};
    const int k0 = wv * (FDIM / 4);
    for (int k = k0; k < k0 + FDIM / 4; k += 8) {
        float w[8];
#pragma unroll
        for (int u = 0; u < 8; u++) w[u] = W[(k + u) * DH + lane];
#pragma unroll
        for (int r = 0; r < 2; r++) {
            float4 a0 = *reinterpret_cast<const float4*>(&h_s[r][k]);
            float4 a1 = *reinterpret_cast<const float4*>(&h_s[r][k + 4]);
            acc2[r] = fmaf(a0.x, w[0], fmaf(a0.y, w[1], fmaf(a0.z, w[2], fmaf(a0.w, w[3], acc2[r]))));
            acc2[r] = fmaf(a1.x, w[4], fmaf(a1.y, w[5], fmaf(a1.z, w[6], fmaf(a1.w, w[7], acc2[r]))));
        }
    }
#pragma unroll
    for (int r = 0; r < 2; r++) part[wv][r][lane] = acc2[r];
    __syncthreads();

    if (wv < 2) {
        const int onode = blockIdx.x * 2 + wv;
        float xv = part[0][wv][lane] + part[1][wv][lane]
                 + part[2][wv][lane] + part[3][wv][lane];
        x_out[(size_t)onode * DH + lane] = xv;
#pragma unroll
        for (int hh = 0; hh < PROJ_H; hh++) {
            float vl = xv * al[lane * PROJ_H + hh];
            float vr = xv * ar[lane * PROJ_H + hh];
#pragma unroll
            for (int off = 32; off >= 1; off >>= 1) {
                vl += __shfl_xor(vl, off, 64);
                vr += __shfl_xor(vr, off, 64);
            }
            if (lane == 0) {
                el_out[onode * PROJ_H + hh] = vl;
                er_out[onode * PROJ_H + hh] = vr;
            }
        }
    }
}

// ---------------------------------------------------------------------------
// Kernel 4: final aggregate (H=1, no activation) -> d_out. Unchanged from
// the proven R1 version (weights-first, LDS broadcasts, 8-deep unroll).
// ---------------------------------------------------------------------------
__global__ __launch_bounds__(256) void k_agg_final(
    const float* __restrict__ x_in, const float* __restrict__ el_in,
    const float* __restrict__ er_in, const int* __restrict__ nbr,
    const int* __restrict__ deg, const float* __restrict__ bias,
    float* __restrict__ out)
{
    __shared__ float ws4[4][CAP];   // 2 KB
    __shared__ int   js4[4][CAP];   // 2 KB
    const int wv = threadIdx.x >> 6;
    const int node = blockIdx.x * 4 + wv;
    const int lane = threadIdx.x & 63;
    const float eli = el_in[node];
    const int dg = deg[node];
    const int* nb = nbr + (size_t)node * CAP;

    const int nbr0 = nb[lane];
    const int nbr1 = nb[64 + lane];
    const int nr = (dg + 63) >> 6;   // rounds of 64 (<= 2)
    float denp = 0.f;
    for (int r = 0; r < nr; r++) {
        const int jj = r * 64 + lane;
        const int jraw = r ? nbr1 : nbr0;
        const bool val = jj < dg;
        const int j = val ? jraw : 0;
        const float e = er_in[j];
        float s = eli + e;
        s = s > 0.f ? s : 0.2f * s;
        const float w = val ? __expf(s) : 0.f;
        ws4[wv][jj] = w;
        js4[wv][jj] = j;
        denp += w;
    }
#pragma unroll
    for (int off = 32; off >= 1; off >>= 1) denp += __shfl_xor(denp, off, 64);

    float acc = 0.f;
    const int cmax = (dg + 7) & ~7;  // entries [dg, cmax) were padded w=0
    for (int c = 0; c < cmax; c += 8) {
#pragma unroll
        for (int u = 0; u < 8; u++) {
            const int j = js4[wv][c + u];
            const float w = ws4[wv][c + u];
            const float xv = x_in[(size_t)j * DH + lane];
            acc = fmaf(w, xv, acc);
        }
    }
    out[(size_t)node * DH + lane] = acc / fmaxf(denp, 1e-12f) + bias[lane];
}

// ---------------------------------------------------------------------------
extern "C" void kernel_launch(void* const* d_in, const int* in_sizes, int n_in,
                              void* d_out, int out_size, void* d_ws, size_t ws_size,
                              hipStream_t stream)
{
    const float* adj  = (const float*)d_in[0];
    const float* feat = (const float*)d_in[1];
    const float* W0   = (const float*)d_in[2];
    const float* al0  = (const float*)d_in[3];
    const float* ar0  = (const float*)d_in[4];
    const float* b0   = (const float*)d_in[5];
    const float* W1   = (const float*)d_in[6];
    const float* al1  = (const float*)d_in[7];
    const float* ar1  = (const float*)d_in[8];
    const float* b1   = (const float*)d_in[9];
    const float* W2   = (const float*)d_in[10];
    const float* al2  = (const float*)d_in[11];
    const float* ar2  = (const float*)d_in[12];
    const float* b2   = (const float*)d_in[13];
    float* out = (float*)d_out;

    char* ws = (char*)d_ws;
    int*   nbr = (int*)ws;   ws += (size_t)NNODES * CAP * sizeof(int);   // 2 MB
    int*   deg = (int*)ws;   ws += (size_t)NNODES * sizeof(int);         // 16 KB
    float* x0  = (float*)ws; ws += (size_t)NNODES * DH * sizeof(float);  // 1 MB
    float* x1  = (float*)ws; ws += (size_t)NNODES * DH * sizeof(float);  // 1 MB
    float* elA = (float*)ws; ws += (size_t)NNODES * 8 * sizeof(float);   // 128 KB
    float* erA = (float*)ws; ws += (size_t)NNODES * 8 * sizeof(float);   // 128 KB
    float* elB = (float*)ws; ws += (size_t)NNODES * 8 * sizeof(float);   // 128 KB
    float* erB = (float*)ws; ws += (size_t)NNODES * 8 * sizeof(float);   // 128 KB

    // K1: layer-0 mm/proj (blocks 0..1023, first) + build (4096 blocks)
    k_mm0_build<<<NNODES / 4 + NNODES, 256, 0, stream>>>(
        adj, nbr, deg, feat, W0, al0, ar0, x0, elA, erA);

    // K2: agg0 + mm1/proj1   (x0,elA,erA -> x1,elB,erB)  [2 nodes/block]
    k_agg_mm<8><<<NNODES / 2, 256, 0, stream>>>(
        x0, elA, erA, nbr, deg, b0, W1, al1, ar1, x1, elB, erB);

    // K3: agg1 + mm2/proj2   (x1,elB,erB -> x0,elA,erA; PROJ_H=1)
    k_agg_mm<1><<<NNODES / 2, 256, 0, stream>>>(
        x1, elB, erB, nbr, deg, b1, W2, al2, ar2, x0, elA, erA);

    // K4: final aggregate (H=1, no act) -> out
    k_agg_final<<<NNODES / 4, 256, 0, stream>>>(x0, elA, erA, nbr, deg, b2, out);
}